// Round 1
// baseline (18803.465 us; speedup 1.0000x reference)
//
#include <hip/hip_runtime.h>
#include <hip/hip_bf16.h>

// Decoder: B=2048, T=256, H=512(ENC), P=64 parts, PD=32, AD=128, V=12.
// Sequential scan over T. Per step:
//   GEMM_A: gates[b, 0:2304] = h_bf16[b,0:512] @ Wcat^T   (Wcat rows: W_hh(2048), Uw(128), betaw(32), zeros(96))
//   attn:   score/softmax/ctx per b (wave-per-b), writes alphas + inp_bf16[b,0:44]
//   GEMM_B: gates[b, 0:2048] += inp_bf16[b,0:64] @ Wihp^T (W_ih padded 44->64)
//   cell:   LSTM gates -> c,h update; out = h2@ow^T -> log_softmax -> output
// MFMA 16x16x32 bf16, m92 "B^T input" fragment pattern (guide-verified):
//   A/B: lane l reads row (base + (l&15)), k = 8*(l>>4)+j contiguous 8 bf16
//   C/D: col = l&15, row = (l>>4)*4 + reg

typedef __attribute__((ext_vector_type(8))) short short8;
typedef __attribute__((ext_vector_type(4))) float floatx4;

#define DEV static __device__ __forceinline__

DEV unsigned short f2bf(float f) {
    unsigned int u = __float_as_uint(f);
    unsigned int r = (u + 0x7FFFu + ((u >> 16) & 1u)) >> 16;
    return (unsigned short)r;
}
DEV float bf2f(unsigned short u) { return __uint_as_float(((unsigned int)u) << 16); }
DEV float tanh_f(float x) {
    float ax = fabsf(x);
    float e = __expf(-2.f * ax);
    float t = (1.f - e) / (1.f + e);
    return copysignf(t, x);
}
DEV float sigm(float x) { return 1.f / (1.f + __expf(-x)); }

// ---------------- workspace layout (bytes) ----------------
#define OFF_H      ((size_t)0)                       // h bf16 [2048][512]   2 MB
#define OFF_C      ((size_t)2097152)                 // c f32  [2048][512]   4 MB
#define OFF_G      ((size_t)6291456)                 // gates f32 [2048][2304] 18.9 MB
#define OFF_WS     ((size_t)25165824)                // Ws bf16 [2048][64][128] 33.5 MB
#define OFF_PARTS  ((size_t)58720256)                // parts f32 [2048][64][32] 16.8 MB
#define OFF_AVG    ((size_t)75497472)                // avg f32 [2048][64] 0.5 MB
#define OFF_WCAT   ((size_t)76021760)                // Wcat bf16 [2304][512] 2.25 MB
#define OFF_WIHP   ((size_t)78381056)                // Wihp bf16 [2048][64]
#define OFF_INP    ((size_t)78643200)                // inp bf16 [2048][64]
// total ~78.9 MB

// avg[b,p] = mean over 32 channels of img[b, k, p]
__global__ void k_avg(const float* __restrict__ img, float* __restrict__ avg) {
    int idx = blockIdx.x * 256 + threadIdx.x;  // 2048*64
    int b = idx >> 6, p = idx & 63;
    const float* base = img + (size_t)b * 2048 + p;
    float s = 0.f;
#pragma unroll
    for (int k = 0; k < 32; ++k) s += base[k * 64];
    avg[idx] = s * (1.f / 32.f);
}

// Wcat / Wihp bf16 conversion + zero-pad inp[44:64]
__global__ void k_prep(const float* __restrict__ Whh, const float* __restrict__ Uw,
                       const float* __restrict__ betaw, const float* __restrict__ Wih,
                       unsigned short* __restrict__ Wcat, unsigned short* __restrict__ Wihp,
                       unsigned short* __restrict__ inp_bf) {
    int idx = blockIdx.x * 256 + threadIdx.x;
    if (idx < 2304 * 512) {
        int n = idx >> 9, k = idx & 511;
        float v = 0.f;
        if (n < 2048) v = Whh[idx];
        else if (n < 2176) v = Uw[(n - 2048) * 512 + k];
        else if (n < 2208) v = betaw[(n - 2176) * 512 + k];
        Wcat[idx] = f2bf(v);
    }
    if (idx < 2048 * 64) {
        int n = idx >> 6, m = idx & 63;
        float v = (m < 44) ? Wih[n * 44 + m] : 0.f;
        Wihp[idx] = f2bf(v);
        if (m >= 44) inp_bf[idx] = 0;  // constant zero pad, rewritten every launch
    }
}

// h0 = tanh(avg@ihw^T + ihb) -> bf16; c0 = tanh(avg@icw^T + icb) -> f32
__global__ __launch_bounds__(512) void k_h0c0(const float* __restrict__ avg,
                                              const float* __restrict__ ihw, const float* __restrict__ ihb,
                                              const float* __restrict__ icw, const float* __restrict__ icb,
                                              unsigned short* __restrict__ h_bf, float* __restrict__ c) {
    __shared__ float avg_s[8][64];
    int b0 = blockIdx.x * 8, tid = threadIdx.x;
    for (int i = tid; i < 8 * 64; i += 512) avg_s[i >> 6][i & 63] = avg[b0 * 64 + i];
    __syncthreads();
    int j = tid;
    float w0[64];
#pragma unroll
    for (int p4 = 0; p4 < 16; ++p4) {
        float4 v = ((const float4*)(ihw + j * 64))[p4];
        w0[p4 * 4 + 0] = v.x; w0[p4 * 4 + 1] = v.y; w0[p4 * 4 + 2] = v.z; w0[p4 * 4 + 3] = v.w;
    }
    float bh = ihb[j];
#pragma unroll
    for (int bb = 0; bb < 8; ++bb) {
        float s = bh;
#pragma unroll
        for (int p = 0; p < 64; ++p) s += w0[p] * avg_s[bb][p];
        h_bf[(size_t)(b0 + bb) * 512 + j] = f2bf(tanh_f(s));
    }
#pragma unroll
    for (int p4 = 0; p4 < 16; ++p4) {
        float4 v = ((const float4*)(icw + j * 64))[p4];
        w0[p4 * 4 + 0] = v.x; w0[p4 * 4 + 1] = v.y; w0[p4 * 4 + 2] = v.z; w0[p4 * 4 + 3] = v.w;
    }
    float bc = icb[j];
#pragma unroll
    for (int bb = 0; bb < 8; ++bb) {
        float s = bc;
#pragma unroll
        for (int p = 0; p < 64; ++p) s += w0[p] * avg_s[bb][p];
        c[(size_t)(b0 + bb) * 512 + j] = tanh_f(s);
    }
}

// Ws[b,p,d] = bf16( sum_k parts[b,p,k]*Ww[d,k] + Wb[d] ); also stores parts f32
__global__ __launch_bounds__(256) void k_ws(const float* __restrict__ img, const float* __restrict__ Ww,
                                            const float* __restrict__ Wb, unsigned short* __restrict__ Ws,
                                            float* __restrict__ parts) {
    __shared__ float pl[64][33];    // parts[p][k], padded
    __shared__ float wl[32 * 128];  // Ww transposed: wl[k*128 + d]
    int b = blockIdx.x, tid = threadIdx.x;
    const float* ib = img + (size_t)b * 2048;
    for (int i = tid; i < 2048; i += 256) pl[i & 63][i >> 6] = ib[i];          // img[b,k,p] -> pl[p][k]
    for (int i = tid; i < 4096; i += 256) wl[(i & 31) * 128 + (i >> 5)] = Ww[i];  // Ww[d*32+k]
    __syncthreads();
    for (int i = tid; i < 2048; i += 256) parts[(size_t)b * 2048 + i] = pl[i >> 5][i & 31];
#pragma unroll
    for (int r = 0; r < 32; ++r) {
        int o = tid + r * 256;      // p = o>>7, d = o&127
        int p = o >> 7, d = o & 127;
        float s = Wb[d];
#pragma unroll
        for (int k = 0; k < 32; ++k) s += pl[p][k] * wl[k * 128 + d];
        Ws[(size_t)b * 8192 + o] = f2bf(s);
    }
}

// GEMM_A: gates[2048][2304] = h_bf[2048][512] @ Wcat[2304][512]^T
__global__ __launch_bounds__(256) void k_gemm_a(const unsigned short* __restrict__ A,
                                                const unsigned short* __restrict__ Bw,
                                                float* __restrict__ Cc) {
    int wave = threadIdx.x >> 6, lane = threadIdx.x & 63;
    int mbase = blockIdx.x * 128 + (wave >> 1) * 64;
    int nbase = blockIdx.y * 128 + (wave & 1) * 64;
    int mrow = lane & 15, kcol = (lane >> 4) * 8;
    floatx4 acc[4][4] = {};
    const unsigned short* Ap = A + (size_t)(mbase + mrow) * 512 + kcol;
    const unsigned short* Bp = Bw + (size_t)(nbase + mrow) * 512 + kcol;
    for (int k0 = 0; k0 < 512; k0 += 32) {
        short8 a[4], b[4];
#pragma unroll
        for (int i = 0; i < 4; ++i) a[i] = *(const short8*)(Ap + (size_t)i * 16 * 512 + k0);
#pragma unroll
        for (int j = 0; j < 4; ++j) b[j] = *(const short8*)(Bp + (size_t)j * 16 * 512 + k0);
#pragma unroll
        for (int i = 0; i < 4; ++i)
#pragma unroll
            for (int j = 0; j < 4; ++j)
                acc[i][j] = __builtin_amdgcn_mfma_f32_16x16x32_bf16(a[i], b[j], acc[i][j], 0, 0, 0);
    }
    int r0 = (lane >> 4) * 4, cc = lane & 15;
#pragma unroll
    for (int i = 0; i < 4; ++i)
#pragma unroll
        for (int j = 0; j < 4; ++j) {
            size_t base = (size_t)(mbase + i * 16 + r0) * 2304 + (size_t)(nbase + j * 16 + cc);
#pragma unroll
            for (int r = 0; r < 4; ++r) Cc[base + (size_t)r * 2304] = acc[i][j][r];
        }
}

// GEMM_B: gates[2048][0:2048] += inp_bf[2048][64] @ Wihp[2048][64]^T
__global__ __launch_bounds__(256) void k_gemm_b(const unsigned short* __restrict__ A,
                                                const unsigned short* __restrict__ Bw,
                                                float* __restrict__ Cc) {
    int wave = threadIdx.x >> 6, lane = threadIdx.x & 63;
    int mbase = blockIdx.x * 128 + (wave >> 1) * 64;
    int nbase = blockIdx.y * 128 + (wave & 1) * 64;
    int mrow = lane & 15, kcol = (lane >> 4) * 8;
    floatx4 acc[4][4] = {};
#pragma unroll
    for (int k0 = 0; k0 < 64; k0 += 32) {
        short8 a[4], b[4];
#pragma unroll
        for (int i = 0; i < 4; ++i) a[i] = *(const short8*)(A + (size_t)(mbase + i * 16 + mrow) * 64 + k0 + kcol);
#pragma unroll
        for (int j = 0; j < 4; ++j) b[j] = *(const short8*)(Bw + (size_t)(nbase + j * 16 + mrow) * 64 + k0 + kcol);
#pragma unroll
        for (int i = 0; i < 4; ++i)
#pragma unroll
            for (int j = 0; j < 4; ++j)
                acc[i][j] = __builtin_amdgcn_mfma_f32_16x16x32_bf16(a[i], b[j], acc[i][j], 0, 0, 0);
    }
    int r0 = (lane >> 4) * 4, cc = lane & 15;
#pragma unroll
    for (int i = 0; i < 4; ++i)
#pragma unroll
        for (int j = 0; j < 4; ++j) {
            size_t base = (size_t)(mbase + i * 16 + r0) * 2304 + (size_t)(nbase + j * 16 + cc);
#pragma unroll
            for (int r = 0; r < 4; ++r) Cc[base + (size_t)r * 2304] += acc[i][j][r];
        }
}

// attention: wave per b. score -> softmax(64 lanes) -> ctx -> inp_bf
__global__ __launch_bounds__(256) void k_attn(const float* __restrict__ gates,
                                              const float* __restrict__ Ub, const float* __restrict__ betab,
                                              const float* __restrict__ vw, const float* __restrict__ vb,
                                              const unsigned short* __restrict__ Ws,
                                              const float* __restrict__ parts,
                                              const float* __restrict__ label,
                                              unsigned short* __restrict__ inp_bf,
                                              float* __restrict__ out_alpha, int t) {
    __shared__ float vws[128];
    __shared__ float uh[4][128];
    __shared__ float al[4][64];
    int tid = threadIdx.x, w = tid >> 6, lane = tid & 63;
    int b = blockIdx.x * 4 + w;
    if (tid < 128) vws[tid] = vw[tid];
    const float* gb = gates + (size_t)b * 2304 + 2048;
    uh[w][lane * 2] = gb[lane * 2] + Ub[lane * 2];
    uh[w][lane * 2 + 1] = gb[lane * 2 + 1] + Ub[lane * 2 + 1];
    __syncthreads();
    const unsigned short* wsb = Ws + ((size_t)b * 64 + lane) * 128;
    float s = vb[0];
#pragma unroll
    for (int d0 = 0; d0 < 128; d0 += 8) {
        short8 wv = *(const short8*)(wsb + d0);
#pragma unroll
        for (int j = 0; j < 8; ++j) {
            float x = bf2f((unsigned short)wv[j]) + uh[w][d0 + j];
            s += vws[d0 + j] * tanh_f(x);
        }
    }
    float m = s;
#pragma unroll
    for (int o = 32; o; o >>= 1) m = fmaxf(m, __shfl_xor(m, o));
    float e = __expf(s - m);
    float sum = e;
#pragma unroll
    for (int o = 32; o; o >>= 1) sum += __shfl_xor(sum, o);
    float alpha = e / sum;
    out_alpha[((size_t)t * 2048 + b) * 64 + lane] = alpha;
    al[w][lane] = alpha;
    __syncthreads();
    int k = lane & 31, half = lane >> 5;
    const float* pb = parts + (size_t)b * 2048;
    float cpart = 0.f;
#pragma unroll
    for (int p = 0; p < 32; ++p) {
        int pp = half * 32 + p;
        cpart += al[w][pp] * pb[pp * 32 + k];
    }
    cpart += __shfl_xor(cpart, 32);
    if (half == 0) {
        float beta = sigm(gates[(size_t)b * 2304 + 2176 + k] + betab[k]);
        inp_bf[b * 64 + 12 + k] = f2bf(cpart * beta);
    }
    if (lane < 12) inp_bf[b * 64 + lane] = f2bf(label[((size_t)b * 256 + t) * 12 + lane]);
}

// LSTM cell + output head + log_softmax. 8 b per block, thread j in [0,512).
__global__ __launch_bounds__(512) void k_cell(const float* __restrict__ gates,
                                              const float* __restrict__ b_ih, const float* __restrict__ b_hh,
                                              float* __restrict__ c, unsigned short* __restrict__ h_bf,
                                              const float* __restrict__ ow, const float* __restrict__ ob,
                                              float* __restrict__ out_logits, int t) {
    __shared__ float h2s[8][512];
    __shared__ float outs[8][12];
    int tid = threadIdx.x, b0 = blockIdx.x * 8, j = tid;
    float bi = b_ih[j] + b_hh[j];
    float bf_ = b_ih[512 + j] + b_hh[512 + j];
    float bg = b_ih[1024 + j] + b_hh[1024 + j];
    float bo = b_ih[1536 + j] + b_hh[1536 + j];
#pragma unroll
    for (int bb = 0; bb < 8; ++bb) {
        size_t gbase = (size_t)(b0 + bb) * 2304;
        float gi = gates[gbase + j] + bi;
        float gf = gates[gbase + 512 + j] + bf_;
        float gg = gates[gbase + 1024 + j] + bg;
        float go = gates[gbase + 1536 + j] + bo;
        size_t hc = (size_t)(b0 + bb) * 512 + j;
        float cold = c[hc];
        float c2 = sigm(gf) * cold + sigm(gi) * tanh_f(gg);
        float h2 = sigm(go) * tanh_f(c2);
        c[hc] = c2;
        h_bf[hc] = f2bf(h2);
        h2s[bb][j] = h2;
    }
    __syncthreads();
    int w = tid >> 6, lane = tid & 63;  // wave w handles b0+w
#pragma unroll
    for (int v = 0; v < 12; ++v) {
        const float* owr = ow + v * 512;
        float p = 0.f;
#pragma unroll
        for (int q = 0; q < 8; ++q) p += h2s[w][lane + q * 64] * owr[lane + q * 64];
#pragma unroll
        for (int o = 32; o; o >>= 1) p += __shfl_xor(p, o);
        if (lane == 0) outs[w][v] = p + ob[v];
    }
    __syncthreads();
    float x = (lane < 12) ? outs[w][lane] : -1e30f;
    float lse = 0.f;
    if (lane == 0) {
        float mx = outs[w][0];
#pragma unroll
        for (int v = 1; v < 12; ++v) mx = fmaxf(mx, outs[w][v]);
        float ssum = 0.f;
#pragma unroll
        for (int v = 0; v < 12; ++v) ssum += __expf(outs[w][v] - mx);
        lse = mx + __logf(ssum);
    }
    lse = __shfl(lse, 0);
    if (lane < 12) out_logits[((size_t)(b0 + w) * 256 + t) * 12 + lane] = x - lse;
}

extern "C" void kernel_launch(void* const* d_in, const int* in_sizes, int n_in,
                              void* d_out, int out_size, void* d_ws, size_t ws_size,
                              hipStream_t stream) {
    const float* img   = (const float*)d_in[0];
    const float* label = (const float*)d_in[1];
    const float* Ww    = (const float*)d_in[2];
    const float* Wb    = (const float*)d_in[3];
    const float* Uw    = (const float*)d_in[4];
    const float* Ub    = (const float*)d_in[5];
    const float* vw    = (const float*)d_in[6];
    const float* vb    = (const float*)d_in[7];
    const float* betaw = (const float*)d_in[8];
    const float* betab = (const float*)d_in[9];
    const float* ihw   = (const float*)d_in[10];
    const float* ihb   = (const float*)d_in[11];
    const float* icw   = (const float*)d_in[12];
    const float* icb   = (const float*)d_in[13];
    const float* Wih   = (const float*)d_in[14];
    const float* Whh   = (const float*)d_in[15];
    const float* bih   = (const float*)d_in[16];
    const float* bhh   = (const float*)d_in[17];
    const float* ow    = (const float*)d_in[18];
    const float* ob    = (const float*)d_in[19];

    char* ws = (char*)d_ws;
    unsigned short* h_bf  = (unsigned short*)(ws + OFF_H);
    float*          c     = (float*)(ws + OFF_C);
    float*          gates = (float*)(ws + OFF_G);
    unsigned short* Ws_   = (unsigned short*)(ws + OFF_WS);
    float*          parts = (float*)(ws + OFF_PARTS);
    float*          avg   = (float*)(ws + OFF_AVG);
    unsigned short* Wcat  = (unsigned short*)(ws + OFF_WCAT);
    unsigned short* Wihp  = (unsigned short*)(ws + OFF_WIHP);
    unsigned short* inp   = (unsigned short*)(ws + OFF_INP);

    float* out_logits = (float*)d_out;
    float* out_alpha  = out_logits + (size_t)2048 * 256 * 12;

    k_avg<<<512, 256, 0, stream>>>(img, avg);
    k_prep<<<4608, 256, 0, stream>>>(Whh, Uw, betaw, Wih, Wcat, Wihp, inp);
    k_h0c0<<<256, 512, 0, stream>>>(avg, ihw, ihb, icw, icb, h_bf, c);
    k_ws<<<2048, 256, 0, stream>>>(img, Ww, Wb, Ws_, parts);

    for (int t = 0; t < 256; ++t) {
        k_gemm_a<<<dim3(16, 18), 256, 0, stream>>>(h_bf, Wcat, gates);
        k_attn<<<512, 256, 0, stream>>>(gates, Ub, betab, vw, vb, Ws_, parts, label, inp, out_alpha, t);
        k_gemm_b<<<dim3(16, 16), 256, 0, stream>>>(inp, Wihp, gates);
        k_cell<<<256, 512, 0, stream>>>(gates, bih, bhh, c, h_bf, ow, ob, out_logits, t);
    }
}

// Round 2
// 18375.137 us; speedup vs baseline: 1.0233x; 1.0233x over previous
//
#include <hip/hip_runtime.h>
#include <hip/hip_bf16.h>

// Decoder: B=2048, T=256, H=512, P=64 parts, PD=32, AD=128, V=12.
// Per step (2 kernels):
//   K1: small GEMM (Uh[128]+beta[32] = h @ Wsmall^T, MFMA) + attention (wave/b)
//       + output head for step t-1 (overlapped on waves 4-7).
//       Writes x_t,ctx*beta into xh[...,512:556] (bf16), alphas, logits(t-1).
//   K2: gates = xh[...,0:576] @ Wbig^T (K=576, N=2048 perm rows p=4j+g),
//       LSTM cell fused in epilogue via LDS tile -> writes c (f32), h2 -> other xh buffer.
// gates never touch global memory. xh double-buffered (h-write vs A-read race).
// MFMA 16x16x32 bf16: A/B lane l: row base+(l&15), k=8*(l>>4)+j; C/D col=l&15,row=(l>>4)*4+r.

typedef __attribute__((ext_vector_type(8))) short short8;
typedef __attribute__((ext_vector_type(4))) float floatx4;

#define DEV static __device__ __forceinline__

DEV unsigned short f2bf(float f) {
    unsigned int u = __float_as_uint(f);
    unsigned int r = (u + 0x7FFFu + ((u >> 16) & 1u)) >> 16;
    return (unsigned short)r;
}
DEV float bf2f(unsigned short u) { return __uint_as_float(((unsigned int)u) << 16); }
DEV float tanh_f(float x) {
    float ax = fabsf(x);
    float e = __expf(-2.f * ax);
    float t = (1.f - e) / (1.f + e);
    return copysignf(t, x);
}
DEV float sigm(float x) { return 1.f / (1.f + __expf(-x)); }

// ---------------- workspace layout (bytes) ----------------
#define OFF_XH0    ((size_t)0)          // bf16 [2048][576]  (cols: 0:512 h, 512:524 x, 524:556 ctx*beta, 556:576 zero)
#define OFF_XH1    ((size_t)2359296)
#define OFF_C      ((size_t)4718592)    // f32 [2048][512]
#define OFF_WS2    ((size_t)8912896)    // bf16 [2048][16][64][8]  Ws coalesced layout
#define OFF_PARTS  ((size_t)42467328)   // f32 [2048][64][32]
#define OFF_AVG    ((size_t)59244544)   // f32 [2048][64]
#define OFF_WBIG   ((size_t)59768832)   // bf16 [2048][576], row p=4j+g -> orig row g*512+j
#define OFF_WSMALL ((size_t)62128128)   // bf16 [192][512]: 0:128 Uw, 128:160 betaw, 160:192 zero
#define OFF_BIAS   ((size_t)62324736)   // f32 [2048] b_ih+b_hh (original row order)
// total ~62.3 MB

__global__ void k_avg(const float* __restrict__ img, float* __restrict__ avg) {
    int idx = blockIdx.x * 256 + threadIdx.x;  // 2048*64
    int b = idx >> 6, p = idx & 63;
    const float* base = img + (size_t)b * 2048 + p;
    float s = 0.f;
#pragma unroll
    for (int k = 0; k < 32; ++k) s += base[k * 64];
    avg[idx] = s * (1.f / 32.f);
}

// one block per output row p of Wbig; also Wsmall rows, bias
__global__ void k_prep(const float* __restrict__ Whh, const float* __restrict__ Wih,
                       const float* __restrict__ Uw, const float* __restrict__ betaw,
                       const float* __restrict__ bih, const float* __restrict__ bhh,
                       unsigned short* __restrict__ Wbig, unsigned short* __restrict__ Wsmall,
                       float* __restrict__ bias_cat) {
    int p = blockIdx.x, tid = threadIdx.x;
    int g = p & 3, j = p >> 2, orig = g * 512 + j;
    for (int k = tid; k < 576; k += 256) {
        float v = 0.f;
        if (k < 512) v = Whh[(size_t)orig * 512 + k];
        else if (k < 556) v = Wih[(size_t)orig * 44 + (k - 512)];
        Wbig[(size_t)p * 576 + k] = f2bf(v);
    }
    if (p < 192) {
        for (int k = tid; k < 512; k += 256) {
            float v = 0.f;
            if (p < 128) v = Uw[(size_t)p * 512 + k];
            else if (p < 160) v = betaw[(size_t)(p - 128) * 512 + k];
            Wsmall[(size_t)p * 512 + k] = f2bf(v);
        }
    }
    if (tid == 0) bias_cat[orig] = bih[orig] + bhh[orig];
}

// h0 -> xh0 cols 0:512 (bf16); c0 -> c (f32); zero pad cols 556:576 of both xh bufs
__global__ __launch_bounds__(512) void k_h0c0(const float* __restrict__ avg,
                                              const float* __restrict__ ihw, const float* __restrict__ ihb,
                                              const float* __restrict__ icw, const float* __restrict__ icb,
                                              unsigned short* __restrict__ xh0, unsigned short* __restrict__ xh1,
                                              float* __restrict__ c) {
    __shared__ float avg_s[8][64];
    int b0 = blockIdx.x * 8, tid = threadIdx.x;
    for (int i = tid; i < 8 * 64; i += 512) avg_s[i >> 6][i & 63] = avg[b0 * 64 + i];
    __syncthreads();
    int j = tid;
    float w0[64];
#pragma unroll
    for (int p4 = 0; p4 < 16; ++p4) {
        float4 v = ((const float4*)(ihw + j * 64))[p4];
        w0[p4 * 4 + 0] = v.x; w0[p4 * 4 + 1] = v.y; w0[p4 * 4 + 2] = v.z; w0[p4 * 4 + 3] = v.w;
    }
    float bh = ihb[j];
#pragma unroll
    for (int bb = 0; bb < 8; ++bb) {
        float s = bh;
#pragma unroll
        for (int p = 0; p < 64; ++p) s += w0[p] * avg_s[bb][p];
        xh0[(size_t)(b0 + bb) * 576 + j] = f2bf(tanh_f(s));
        if (j < 20) {
            xh0[(size_t)(b0 + bb) * 576 + 556 + j] = 0;
            xh1[(size_t)(b0 + bb) * 576 + 556 + j] = 0;
        }
    }
#pragma unroll
    for (int p4 = 0; p4 < 16; ++p4) {
        float4 v = ((const float4*)(icw + j * 64))[p4];
        w0[p4 * 4 + 0] = v.x; w0[p4 * 4 + 1] = v.y; w0[p4 * 4 + 2] = v.z; w0[p4 * 4 + 3] = v.w;
    }
    float bc = icb[j];
#pragma unroll
    for (int bb = 0; bb < 8; ++bb) {
        float s = bc;
#pragma unroll
        for (int p = 0; p < 64; ++p) s += w0[p] * avg_s[bb][p];
        c[(size_t)(b0 + bb) * 512 + j] = tanh_f(s);
    }
}

// Ws2[b][dg][p][dd] = bf16( parts[b,p] . Ww[d] + Wb[d] ), d=dg*8+dd; also parts f32
__global__ __launch_bounds__(256) void k_ws(const float* __restrict__ img, const float* __restrict__ Ww,
                                            const float* __restrict__ Wb, unsigned short* __restrict__ Ws2,
                                            float* __restrict__ parts) {
    __shared__ float pl[64][33];
    __shared__ float wl[32 * 128];
    int b = blockIdx.x, tid = threadIdx.x;
    const float* ib = img + (size_t)b * 2048;
    for (int i = tid; i < 2048; i += 256) pl[i & 63][i >> 6] = ib[i];
    for (int i = tid; i < 4096; i += 256) wl[(i & 31) * 128 + (i >> 5)] = Ww[i];
    __syncthreads();
    for (int i = tid; i < 2048; i += 256) parts[(size_t)b * 2048 + i] = pl[i >> 5][i & 31];
#pragma unroll
    for (int r = 0; r < 32; ++r) {
        int o = tid + r * 256;
        int p = o >> 7, d = o & 127;
        float s = Wb[d];
#pragma unroll
        for (int k = 0; k < 32; ++k) s += pl[p][k] * wl[k * 128 + d];
        Ws2[(size_t)b * 8192 + (size_t)(d >> 3) * 512 + p * 8 + (d & 7)] = f2bf(s);
    }
}

// K1: small GEMM + attention + output head (t-1). 8 b's per block, 512 thr.
__global__ __launch_bounds__(512) void k1(unsigned short* __restrict__ xh,
                                          const unsigned short* __restrict__ Wsmall,
                                          const float* __restrict__ Ub, const float* __restrict__ betab,
                                          const float* __restrict__ vw, const float* __restrict__ vb,
                                          const unsigned short* __restrict__ Ws2,
                                          const float* __restrict__ parts,
                                          const float* __restrict__ label,
                                          const float* __restrict__ ow, const float* __restrict__ ob,
                                          float* __restrict__ out_alpha, float* __restrict__ out_logits,
                                          int t, int do_attn, int do_out) {
    __shared__ float uhl[8][192];
    __shared__ float vws[128];
    __shared__ float ows[12][512];
    __shared__ float al[8][64];
    __shared__ float outs[8][12];
    int tid = threadIdx.x, w = tid >> 6, lane = tid & 63;
    int b0 = blockIdx.x * 8;
    if (tid < 128) vws[tid] = vw[tid];
    if (do_out) {
        for (int i = tid; i < 12 * 512; i += 512) ows[i >> 9][i & 511] = ow[i];
    }
    __syncthreads();
    if (do_attn && w < 4) {
        // small GEMM: M=16 (8 real b), wave w covers n in [48w, 48w+48)
        int mr = b0 + (lane & 15); if (mr > 2047) mr = 2047;
        const unsigned short* Ap = xh + (size_t)mr * 576 + (lane >> 4) * 8;
        const unsigned short* Bp = Wsmall + (size_t)(48 * w + (lane & 15)) * 512 + (lane >> 4) * 8;
        floatx4 acc[3] = {};
        for (int k0 = 0; k0 < 512; k0 += 32) {
            short8 a = *(const short8*)(Ap + k0);
#pragma unroll
            for (int jt = 0; jt < 3; ++jt) {
                short8 bb = *(const short8*)(Bp + (size_t)jt * 16 * 512 + k0);
                acc[jt] = __builtin_amdgcn_mfma_f32_16x16x32_bf16(a, bb, acc[jt], 0, 0, 0);
            }
        }
        int cc = lane & 15, r0 = (lane >> 4) * 4;
#pragma unroll
        for (int jt = 0; jt < 3; ++jt)
#pragma unroll
            for (int r = 0; r < 4; ++r) {
                int m = r0 + r, n = 48 * w + jt * 16 + cc;
                if (m < 8 && n < 160) uhl[m][n] = acc[jt][r] + (n < 128 ? Ub[n] : betab[n - 128]);
            }
    }
    if (do_out && w >= 4) {
        // output head for step t-1: waves 4-7, 2 b's each
#pragma unroll
        for (int u = 0; u < 2; ++u) {
            int bl = (w - 4) * 2 + u;
            int b = b0 + bl;
            const unsigned short* hp = xh + (size_t)b * 576;
            float hreg[8];
#pragma unroll
            for (int q = 0; q < 8; ++q) hreg[q] = bf2f(hp[lane + 64 * q]);
#pragma unroll
            for (int v = 0; v < 12; ++v) {
                float p = 0.f;
#pragma unroll
                for (int q = 0; q < 8; ++q) p += hreg[q] * ows[v][lane + 64 * q];
#pragma unroll
                for (int o = 32; o; o >>= 1) p += __shfl_xor(p, o);
                if (lane == 0) outs[bl][v] = p + ob[v];
            }
            float x = (lane < 12) ? outs[bl][lane] : -1e30f;
            float lse = 0.f;
            if (lane == 0) {
                float mx = outs[bl][0];
#pragma unroll
                for (int v = 1; v < 12; ++v) mx = fmaxf(mx, outs[bl][v]);
                float ssum = 0.f;
#pragma unroll
                for (int v = 0; v < 12; ++v) ssum += __expf(outs[bl][v] - mx);
                lse = mx + __logf(ssum);
            }
            lse = __shfl(lse, 0);
            if (lane < 12) out_logits[((size_t)b * 256 + (t - 1)) * 12 + lane] = x - lse;
        }
    }
    __syncthreads();
    if (do_attn) {
        int b = b0 + w;   // wave per b, lane = part p
        const unsigned short* wsp = Ws2 + (size_t)b * 8192 + lane * 8;
        float s = vb[0];
#pragma unroll
        for (int dg = 0; dg < 16; ++dg) {
            short8 wv8 = *(const short8*)(wsp + (size_t)dg * 512);
#pragma unroll
            for (int dd = 0; dd < 8; ++dd) {
                int d = dg * 8 + dd;
                s += vws[d] * tanh_f(bf2f((unsigned short)wv8[dd]) + uhl[w][d]);
            }
        }
        float m = s;
#pragma unroll
        for (int o = 32; o; o >>= 1) m = fmaxf(m, __shfl_xor(m, o));
        float e = __expf(s - m);
        float sum = e;
#pragma unroll
        for (int o = 32; o; o >>= 1) sum += __shfl_xor(sum, o);
        float alpha = e / sum;
        out_alpha[((size_t)t * 2048 + b) * 64 + lane] = alpha;
        al[w][lane] = alpha;
        int k = lane & 31, half = lane >> 5;
        const float* pb = parts + (size_t)b * 2048;
        float cpart = 0.f;
#pragma unroll
        for (int p = 0; p < 32; ++p) {
            int pp = half * 32 + p;
            cpart += al[w][pp] * pb[pp * 32 + k];
        }
        cpart += __shfl_xor(cpart, 32);
        if (half == 0) {
            float beta = sigm(uhl[w][128 + k]);
            xh[(size_t)b * 576 + 524 + k] = f2bf(cpart * beta);
        }
        if (lane < 12) xh[(size_t)b * 576 + 512 + lane] = f2bf(label[((size_t)b * 256 + t) * 12 + lane]);
    }
}

// K2: gates = xh_in @ Wbig^T (K=576) + fused LSTM cell. Tile 64(M) x 128(N), grid (32,16).
__global__ __launch_bounds__(256) void k2(const unsigned short* __restrict__ xh_in,
                                          unsigned short* __restrict__ xh_out,
                                          const unsigned short* __restrict__ Wbig,
                                          const float* __restrict__ bias_cat,
                                          float* __restrict__ c) {
    __shared__ float gt[64][129];   // col = g*32 + jl (un-interleaved)
    int tid = threadIdx.x, w = tid >> 6, lane = tid & 63;
    int mbase = blockIdx.x * 64, nbase = blockIdx.y * 128, jbase = blockIdx.y * 32;
    int wm = w >> 1, wn = w & 1;
    const unsigned short* Ap = xh_in + (size_t)(mbase + wm * 32 + (lane & 15)) * 576 + (lane >> 4) * 8;
    const unsigned short* Bp = Wbig + (size_t)(nbase + wn * 64 + (lane & 15)) * 576 + (lane >> 4) * 8;
    floatx4 acc[2][4] = {};
    for (int k0 = 0; k0 < 576; k0 += 32) {
        short8 a[2], b[4];
#pragma unroll
        for (int i = 0; i < 2; ++i) a[i] = *(const short8*)(Ap + (size_t)i * 16 * 576 + k0);
#pragma unroll
        for (int j = 0; j < 4; ++j) b[j] = *(const short8*)(Bp + (size_t)j * 16 * 576 + k0);
#pragma unroll
        for (int i = 0; i < 2; ++i)
#pragma unroll
            for (int j = 0; j < 4; ++j)
                acc[i][j] = __builtin_amdgcn_mfma_f32_16x16x32_bf16(a[i], b[j], acc[i][j], 0, 0, 0);
    }
    int cc = lane & 15, r0 = (lane >> 4) * 4;
#pragma unroll
    for (int i = 0; i < 2; ++i)
#pragma unroll
        for (int jt = 0; jt < 4; ++jt) {
            int pl = wn * 64 + jt * 16 + cc;
            int colb = (pl & 3) * 32 + (pl >> 2);
            int mlb = wm * 32 + i * 16 + r0;
#pragma unroll
            for (int r = 0; r < 4; ++r) gt[mlb + r][colb] = acc[i][jt][r];
        }
    __syncthreads();
    int jl = tid & 31;
    int j = jbase + jl;
    float bi = bias_cat[j];
    float bfv = bias_cat[512 + j];
    float bg = bias_cat[1024 + j];
    float bo = bias_cat[1536 + j];
#pragma unroll
    for (int it = 0; it < 8; ++it) {
        int bl = (tid >> 5) * 8 + it;
        int b = mbase + bl;
        float gi = gt[bl][jl] + bi;
        float gf = gt[bl][32 + jl] + bfv;
        float gg = gt[bl][64 + jl] + bg;
        float go = gt[bl][96 + jl] + bo;
        size_t hc = (size_t)b * 512 + j;
        float cold = c[hc];
        float c2 = sigm(gf) * cold + sigm(gi) * tanh_f(gg);
        float h2 = sigm(go) * tanh_f(c2);
        c[hc] = c2;
        xh_out[(size_t)b * 576 + j] = f2bf(h2);
    }
}

extern "C" void kernel_launch(void* const* d_in, const int* in_sizes, int n_in,
                              void* d_out, int out_size, void* d_ws, size_t ws_size,
                              hipStream_t stream) {
    const float* img   = (const float*)d_in[0];
    const float* label = (const float*)d_in[1];
    const float* Ww    = (const float*)d_in[2];
    const float* Wb    = (const float*)d_in[3];
    const float* Uw    = (const float*)d_in[4];
    const float* Ub    = (const float*)d_in[5];
    const float* vw    = (const float*)d_in[6];
    const float* vb    = (const float*)d_in[7];
    const float* betaw = (const float*)d_in[8];
    const float* betab = (const float*)d_in[9];
    const float* ihw   = (const float*)d_in[10];
    const float* ihb   = (const float*)d_in[11];
    const float* icw   = (const float*)d_in[12];
    const float* icb   = (const float*)d_in[13];
    const float* Wih   = (const float*)d_in[14];
    const float* Whh   = (const float*)d_in[15];
    const float* bih   = (const float*)d_in[16];
    const float* bhh   = (const float*)d_in[17];
    const float* ow    = (const float*)d_in[18];
    const float* ob    = (const float*)d_in[19];

    char* ws = (char*)d_ws;
    unsigned short* xh0    = (unsigned short*)(ws + OFF_XH0);
    unsigned short* xh1    = (unsigned short*)(ws + OFF_XH1);
    float*          c      = (float*)(ws + OFF_C);
    unsigned short* Ws2    = (unsigned short*)(ws + OFF_WS2);
    float*          parts  = (float*)(ws + OFF_PARTS);
    float*          avg    = (float*)(ws + OFF_AVG);
    unsigned short* Wbig   = (unsigned short*)(ws + OFF_WBIG);
    unsigned short* Wsmall = (unsigned short*)(ws + OFF_WSMALL);
    float*          bias   = (float*)(ws + OFF_BIAS);

    float* out_logits = (float*)d_out;
    float* out_alpha  = out_logits + (size_t)2048 * 256 * 12;

    k_avg<<<512, 256, 0, stream>>>(img, avg);
    k_prep<<<2048, 256, 0, stream>>>(Whh, Wih, Uw, betaw, bih, bhh, Wbig, Wsmall, bias);
    k_h0c0<<<256, 512, 0, stream>>>(avg, ihw, ihb, icw, icb, xh0, xh1, c);
    k_ws<<<2048, 256, 0, stream>>>(img, Ww, Wb, Ws2, parts);

    for (int t = 0; t < 256; ++t) {
        unsigned short* xin  = (t & 1) ? xh1 : xh0;
        unsigned short* xout = (t & 1) ? xh0 : xh1;
        k1<<<256, 512, 0, stream>>>(xin, Wsmall, Ub, betab, vw, vb, Ws2, parts, label,
                                    ow, ob, out_alpha, out_logits, t, 1, t > 0);
        k2<<<dim3(32, 16), 256, 0, stream>>>(xin, xout, Wbig, bias, c);
    }
    // final output head for t=255 (h_256 lives in xh0)
    k1<<<256, 512, 0, stream>>>(xh0, Wsmall, Ub, betab, vw, vb, Ws2, parts, label,
                                ow, ob, out_alpha, out_logits, 256, 0, 1);
}